// Round 10
// baseline (1127.480 us; speedup 1.0000x reference)
//
#include <hip/hip_runtime.h>
#include <hip/hip_bf16.h>
#include <stdint.h>

typedef int  iv4   __attribute__((ext_vector_type(4)));   // 16 i8 operand / i32x4 acc
typedef float f32x4 __attribute__((ext_vector_type(4)));

#define K_DIM 4096
#define N_DIM 4096
#define BK    64      // K-tile depth (i8 elems = bytes)

// ---------------------------------------------------------------------------
// Kernel 1: x fp32 -> i8 with per-row scale sx[row] = rowmax/127.
// ---------------------------------------------------------------------------
__global__ __launch_bounds__(256) void convert_x_i8(const float* __restrict__ x,
                                                    char* __restrict__ xq,
                                                    float* __restrict__ sx) {
    const int row = blockIdx.x;
    const int tid = threadIdx.x;
    const float* xr = x + (long long)row * K_DIM + tid * 16;

    float4 v0 = *(const float4*)(xr + 0);
    float4 v1 = *(const float4*)(xr + 4);
    float4 v2 = *(const float4*)(xr + 8);
    float4 v3 = *(const float4*)(xr + 12);

    float m = fabsf(v0.x);
    m = fmaxf(m, fabsf(v0.y)); m = fmaxf(m, fabsf(v0.z)); m = fmaxf(m, fabsf(v0.w));
    m = fmaxf(m, fabsf(v1.x)); m = fmaxf(m, fabsf(v1.y)); m = fmaxf(m, fabsf(v1.z)); m = fmaxf(m, fabsf(v1.w));
    m = fmaxf(m, fabsf(v2.x)); m = fmaxf(m, fabsf(v2.y)); m = fmaxf(m, fabsf(v2.z)); m = fmaxf(m, fabsf(v2.w));
    m = fmaxf(m, fabsf(v3.x)); m = fmaxf(m, fabsf(v3.y)); m = fmaxf(m, fabsf(v3.z)); m = fmaxf(m, fabsf(v3.w));

    #pragma unroll
    for (int d = 32; d > 0; d >>= 1) m = fmaxf(m, __shfl_xor(m, d));
    __shared__ float red[4];
    const int lane = tid & 63, wid = tid >> 6;
    if (lane == 0) red[wid] = m;
    __syncthreads();
    float rmax = fmaxf(fmaxf(red[0], red[1]), fmaxf(red[2], red[3]));
    rmax = fmaxf(rmax, 1e-20f);
    if (tid == 0) sx[row] = rmax * (1.0f / 127.0f);

    const float q = 127.0f / rmax;
    union { char c[16]; int4 v; } u;
    const float vals[16] = {v0.x, v0.y, v0.z, v0.w, v1.x, v1.y, v1.z, v1.w,
                            v2.x, v2.y, v2.z, v2.w, v3.x, v3.y, v3.z, v3.w};
    #pragma unroll
    for (int i = 0; i < 16; ++i) u.c[i] = (char)__float2int_rn(vals[i] * q);
    *(int4*)(xq + (long long)row * K_DIM + tid * 16) = u.v;
}

// ---------------------------------------------------------------------------
// Kernel 2: weight row -> sign (i8, exact) + per-row mean|w| (fp32)
// ---------------------------------------------------------------------------
__global__ __launch_bounds__(256) void convert_w_i8(const float* __restrict__ w,
                                                    char* __restrict__ wq,
                                                    float* __restrict__ sw) {
    const int row = blockIdx.x;
    const int tid = threadIdx.x;
    const float* wr = w + (long long)row * K_DIM + tid * 16;

    float sum = 0.f;
    union { char c[16]; int4 v; } u;
    #pragma unroll
    for (int j = 0; j < 4; ++j) {
        float4 v = *(const float4*)(wr + j * 4);
        sum += fabsf(v.x) + fabsf(v.y) + fabsf(v.z) + fabsf(v.w);
        u.c[j * 4 + 0] = (char)((v.x > 0.f) - (v.x < 0.f));
        u.c[j * 4 + 1] = (char)((v.y > 0.f) - (v.y < 0.f));
        u.c[j * 4 + 2] = (char)((v.z > 0.f) - (v.z < 0.f));
        u.c[j * 4 + 3] = (char)((v.w > 0.f) - (v.w < 0.f));
    }
    *(int4*)(wq + (long long)row * K_DIM + tid * 16) = u.v;

    #pragma unroll
    for (int d = 32; d > 0; d >>= 1) sum += __shfl_down(sum, d);
    __shared__ float red[4];
    const int lane = tid & 63, wid = tid >> 6;
    if (lane == 0) red[wid] = sum;
    __syncthreads();
    if (tid == 0) sw[row] = (red[0] + red[1] + red[2] + red[3]) * (1.0f / (float)K_DIM);
}

// ===========================================================================
// 256x256 i8 GEMM, 4 WAVES (2x2), wave tile 128x128, acc[8][8] (256 regs).
// LDS redundancy halves (A,B each read 2x -> 128 B/K-elem vs 192) and
// per-wave MFMA doubles -> MFMA-bound regime (2610 vs ~1800 port cyc/tile).
// No intra-tile acc chaining (each acc element gets 1 MFMA per K-tile).
// 2 blocks/CU (64 KiB LDS each) destagger across barriers naturally.
// Sync skeleton = round-9's proven stagger (BK=64, 4 quadrant phases):
//   P0: read a0(4)+b0(4) | stage Ah1(t+1) | q00(a0,b0)
//   P1: read b1(4)       | stage Bh0(t+1) | q01(a0,b1)
//   P2: read a1(4)->a    | stage Bh1(t+1) | q11(a1,b1)
//   P3: -                | stage Ah0(t+2)->CUR buf | q10(a1,b0); vmcnt(2)
// Stage call = 2 gload_lds (half-tile 128 rows x 64B, 4 waves).
// FIFO: end-P3 outstanding = Ah0(t+1)[2] + {Ah1,Bh0,Bh1}(t+1)[6] +
//   Ah0(t+2)[2] = 10 -> vmcnt(2) drains oldest 8 = exactly tile t+1.
// Quadrant order q00->q01->q11->q10: a0 dies before a1 loads (reg liveness).
// Swizzle = round-6's 64B-row pattern (measured 0 conflicts), rule #21.
// ===========================================================================
struct SOp { const char* g; int row0; int kt; char* l; };

// stage one half-tile (128 rows x 64B): 2 gload_lds per wave (4 waves)
__device__ __forceinline__ void stage_half(const SOp s, int wid, int lane) {
    const int srcoff = s.kt + ((((lane & 3) ^ ((lane >> 3) & 3))) << 4);
    #pragma unroll
    for (int op = 0; op < 2; ++op) {
        const int r = s.row0 + wid * 32 + op * 16 + (lane >> 2);
        const char* src = s.g + (long long)r * K_DIM + srcoff;
        __builtin_amdgcn_global_load_lds(
            (const __attribute__((address_space(1))) void*)src,
            (__attribute__((address_space(3))) void*)(s.l + wid * 2048 + op * 1024),
            16, 0, 0);
    }
}

__device__ __forceinline__ iv4 ldsr(const char* t, int row, int c) {
    const int off = row * 64 + ((c ^ ((row >> 1) & 3)) << 4);
    return *(const iv4*)(t + off);
}

// a-half h (64 rows = 4 frags); b-half v (64 rows = 4 frags)
__device__ __forceinline__ void read_ah(iv4 (&a)[4], const char* tA,
                                        int wm, int h, int l15, int c) {
    #pragma unroll
    for (int mi = 0; mi < 4; ++mi)
        a[mi] = ldsr(tA, wm * 128 + h * 64 + mi * 16 + l15, c);
}
__device__ __forceinline__ void read_bv(iv4 (&b)[4], const char* tB,
                                        int wn, int v, int l15, int c) {
    #pragma unroll
    for (int ni = 0; ni < 4; ++ni)
        b[ni] = ldsr(tB, wn * 128 + v * 64 + ni * 16 + l15, c);
}

template<int H, int V>
__device__ __forceinline__ void mfma_q(iv4 (&acc)[8][8],
                                       const iv4 (&a)[4], const iv4 (&b)[4]) {
    #pragma unroll
    for (int mi = 0; mi < 4; ++mi)
        #pragma unroll
        for (int ni = 0; ni < 4; ++ni)
            acc[H * 4 + mi][V * 4 + ni] = __builtin_amdgcn_mfma_i32_16x16x64_i8(
                a[mi], b[ni], acc[H * 4 + mi][V * 4 + ni], 0, 0, 0);
}

// S0..S3: per-phase stage enables. WN: 2 steady / 0 drain / -1 none.
template<bool S0, bool S1, bool S2, bool S3, int WN>
__device__ __forceinline__ void ktile(const char* __restrict__ cA,
                                      const char* __restrict__ cB,
                                      char* __restrict__ oA,
                                      char* __restrict__ oB,
                                      char* __restrict__ curA,
                                      const char* gA, const char* gB,
                                      int ktn, int ktn2,
                                      iv4 (&acc)[8][8],
                                      int wm, int wn, int wid, int lane)
{
    const int l15 = lane & 15;
    const int c   = lane >> 4;
    iv4 a[4], b0[4], b1[4];

    // ---- P0: read a0 + b0 | stage Ah1(t+1) | q00
    read_ah(a, cA, wm, 0, l15, c);
    read_bv(b0, cB, wn, 0, l15, c);
    if constexpr (S0) stage_half({gA, 128, ktn, oA + 8192}, wid, lane);
    __builtin_amdgcn_s_barrier();
    __builtin_amdgcn_s_setprio(1);
    mfma_q<0, 0>(acc, a, b0);
    __builtin_amdgcn_s_setprio(0);
    __builtin_amdgcn_s_barrier();

    // ---- P1: read b1 | stage Bh0(t+1) | q01
    read_bv(b1, cB, wn, 1, l15, c);
    if constexpr (S1) stage_half({gB, 0, ktn, oB}, wid, lane);
    __builtin_amdgcn_s_barrier();
    __builtin_amdgcn_s_setprio(1);
    mfma_q<0, 1>(acc, a, b1);
    __builtin_amdgcn_s_setprio(0);
    __builtin_amdgcn_s_barrier();

    // ---- P2: read a1 (reuses a; a0 dead) | stage Bh1(t+1) | q11
    read_ah(a, cA, wm, 1, l15, c);
    if constexpr (S2) stage_half({gB, 128, ktn, oB + 8192}, wid, lane);
    __builtin_amdgcn_s_barrier();
    __builtin_amdgcn_s_setprio(1);
    mfma_q<1, 1>(acc, a, b1);
    __builtin_amdgcn_s_setprio(0);
    __builtin_amdgcn_s_barrier();

    // ---- P3: stage Ah0(t+2) into CURRENT buf (a0 rows last read @P0) | q10
    if constexpr (S3) stage_half({gA, 0, ktn2, curA}, wid, lane);
    __builtin_amdgcn_s_barrier();
    __builtin_amdgcn_s_setprio(1);
    mfma_q<1, 0>(acc, a, b0);
    __builtin_amdgcn_s_setprio(0);
    if constexpr (WN == 2)      asm volatile("s_waitcnt vmcnt(2)" ::: "memory");
    else if constexpr (WN == 0) asm volatile("s_waitcnt vmcnt(0)" ::: "memory");
    if constexpr (WN >= 0) __builtin_amdgcn_s_barrier();
}

__global__ __launch_bounds__(256, 2) void bitlinear_gemm_i8(
    const char* __restrict__ A, const char* __restrict__ B,
    const float* __restrict__ sx, const float* __restrict__ sw,
    float* __restrict__ C, int M)
{
    extern __shared__ char smem[];
    char* As0 = smem;              // [256][64B] each (16 KiB)
    char* As1 = smem + 16384;
    char* Bs0 = smem + 32768;
    char* Bs1 = smem + 49152;

    const int tid = threadIdx.x, lane = tid & 63, wid = tid >> 6;
    const int wm = wid >> 1, wn = wid & 1;     // 2x2 wave grid

    // T1: bijective XCD swizzle (grid % 8 == 0 guaranteed by launcher)
    const int nbid = (int)blockIdx.x;
    const int cpx  = (int)gridDim.x >> 3;
    const int swz  = (nbid & 7) * cpx + (nbid >> 3);
    const int ntn  = N_DIM / 256;       // 16
    const int tm = swz / ntn, tn = swz % ntn;

    const char* gA = A + (long long)tm * 256 * K_DIM;
    const char* gB = B + (long long)tn * 256 * K_DIM;

    iv4 acc[8][8];
    #pragma unroll
    for (int i = 0; i < 8; ++i)
        #pragma unroll
        for (int j = 0; j < 8; ++j) acc[i][j] = (iv4){0, 0, 0, 0};

    // prologue: t0 all 4 halves + Ah0(t1) = 5 stage calls = 10 loads;
    // vmcnt(2) drains t0's 8, leaves Ah0(t1)'s 2 in flight.
    stage_half({gA,   0,  0, As0},        wid, lane);
    stage_half({gA, 128,  0, As0 + 8192}, wid, lane);
    stage_half({gB,   0,  0, Bs0},        wid, lane);
    stage_half({gB, 128,  0, Bs0 + 8192}, wid, lane);
    stage_half({gA,   0, BK, As1},        wid, lane);
    asm volatile("s_waitcnt vmcnt(2)" ::: "memory");
    __builtin_amdgcn_s_barrier();

    // t=0 (buf0)
    ktile<true, true, true, true, 2>(As0, Bs0, As1, Bs1, As0,
                                     gA, gB, 1 * BK, 2 * BK,
                                     acc, wm, wn, wid, lane);
    // t=1..60 in pairs (buf1, buf0)
    #pragma unroll 1
    for (int i = 0; i < 30; ++i) {
        const int t = 2 * i + 1;
        ktile<true, true, true, true, 2>(As1, Bs1, As0, Bs0, As1,
                                         gA, gB, (t + 1) * BK, (t + 2) * BK,
                                         acc, wm, wn, wid, lane);
        ktile<true, true, true, true, 2>(As0, Bs0, As1, Bs1, As0,
                                         gA, gB, (t + 2) * BK, (t + 3) * BK,
                                         acc, wm, wn, wid, lane);
    }
    // t=61 (buf1): steady (stages t62 halves + Ah0(t63))
    ktile<true, true, true, true, 2>(As1, Bs1, As0, Bs0, As1,
                                     gA, gB, 62 * BK, 63 * BK,
                                     acc, wm, wn, wid, lane);
    // t=62 (buf0): stage t63's Ah1,Bh0,Bh1 only; vmcnt(0) drains all
    ktile<true, true, true, false, 0>(As0, Bs0, As1, Bs1, As0,
                                      gA, gB, 63 * BK, 0,
                                      acc, wm, wn, wid, lane);
    // t=63 (buf1): plain compute, no trailing sync
    ktile<false, false, false, false, -1>(As1, Bs1, As0, Bs0, As1,
                                          gA, gB, 0, 0,
                                          acc, wm, wn, wid, lane);

    // epilogue: out = i32 * sw[col] * sx[row]. C/D: col=lane&15, row=(lane>>4)*4+j
    const long long m0 = (long long)tm * 256 + wm * 128;
    const long long n0 = (long long)tn * 256 + wn * 128;
    float swv[8];
    #pragma unroll
    for (int ni = 0; ni < 8; ++ni) swv[ni] = sw[n0 + ni * 16 + (lane & 15)];
    #pragma unroll
    for (int mi = 0; mi < 8; ++mi) {
        const long long rowb = m0 + mi * 16 + (lane >> 4) * 4;
        float sxr[4];
        #pragma unroll
        for (int j = 0; j < 4; ++j) sxr[j] = sx[rowb + j];
        #pragma unroll
        for (int ni = 0; ni < 8; ++ni) {
            const long long col = n0 + ni * 16 + (lane & 15);
            #pragma unroll
            for (int j = 0; j < 4; ++j)
                C[(rowb + j) * N_DIM + col] = (float)acc[mi][ni][j] * swv[ni] * sxr[j];
        }
    }
}

// ---------------------------------------------------------------------------
// Naive fp32 fallback (shape/workspace escape hatch)
// ---------------------------------------------------------------------------
__global__ void bitlinear_naive_kernel(const float* __restrict__ x,
                                       const float* __restrict__ w,
                                       float* __restrict__ out, long long total) {
    const long long idx = (long long)blockIdx.x * blockDim.x + threadIdx.x;
    if (idx >= total) return;
    const long long m = idx / N_DIM;
    const long long o = idx % N_DIM;
    const float* xr = x + m * K_DIM;
    const float* wrow = w + o * K_DIM;
    float sum = 0.f, sa = 0.f;
    for (int k = 0; k < K_DIM; ++k) {
        float wv = wrow[k];
        sa += fabsf(wv);
        sum += xr[k] * ((wv > 0.f) ? 1.f : ((wv < 0.f) ? -1.f : 0.f));
    }
    out[idx] = sum * (sa * (1.0f / (float)K_DIM));
}

// ---------------------------------------------------------------------------
extern "C" void kernel_launch(void* const* d_in, const int* in_sizes, int n_in,
                              void* d_out, int out_size, void* d_ws, size_t ws_size,
                              hipStream_t stream) {
    const float* x = (const float*)d_in[0];   // [B,S,K] fp32
    const float* w = (const float*)d_in[1];   // [N,K] fp32
    float* out = (float*)d_out;               // [B,S,N] fp32

    const int M = in_sizes[0] / K_DIM;        // 8192

    const size_t xq_bytes = (size_t)M * K_DIM;
    const size_t wq_bytes = (size_t)N_DIM * K_DIM;
    const size_t sx_bytes = (size_t)M * sizeof(float);
    const size_t sw_bytes = (size_t)N_DIM * sizeof(float);

    if (ws_size < xq_bytes + wq_bytes + sx_bytes + sw_bytes || (M % 256) != 0) {
        const long long total = (long long)M * N_DIM;
        bitlinear_naive_kernel<<<(int)((total + 255) / 256), 256, 0, stream>>>(x, w, out, total);
        return;
    }

    char*  xq = (char*)d_ws;
    char*  wq = (char*)d_ws + xq_bytes;
    float* sx = (float*)((char*)d_ws + xq_bytes + wq_bytes);
    float* sw = (float*)((char*)d_ws + xq_bytes + wq_bytes + sx_bytes);

    convert_x_i8<<<M, 256, 0, stream>>>(x, xq, sx);
    convert_w_i8<<<N_DIM, 256, 0, stream>>>(w, wq, sw);

    hipFuncSetAttribute((const void*)bitlinear_gemm_i8,
                        hipFuncAttributeMaxDynamicSharedMemorySize, 65536);
    const int grid = (M / 256) * (N_DIM / 256);   // 32*16 = 512, %8==0
    bitlinear_gemm_i8<<<grid, 256, 65536, stream>>>(xq, wq, sx, sw, out, M);
}

// Round 11
// 186.026 us; speedup vs baseline: 6.0609x; 6.0609x over previous
//
#include <hip/hip_runtime.h>
#include <hip/hip_bf16.h>
#include <stdint.h>

typedef int  iv4   __attribute__((ext_vector_type(4)));   // 16 i8 operand / i32x4 acc
typedef float f32x4 __attribute__((ext_vector_type(4)));

#define K_DIM 4096
#define N_DIM 4096
#define BK    64      // K-tile depth (i8 elems = bytes)

// ---------------------------------------------------------------------------
// Kernel 1: x fp32 -> i8 with per-row scale sx[row] = rowmax/127.
// ---------------------------------------------------------------------------
__global__ __launch_bounds__(256) void convert_x_i8(const float* __restrict__ x,
                                                    char* __restrict__ xq,
                                                    float* __restrict__ sx) {
    const int row = blockIdx.x;
    const int tid = threadIdx.x;
    const float* xr = x + (long long)row * K_DIM + tid * 16;

    float4 v0 = *(const float4*)(xr + 0);
    float4 v1 = *(const float4*)(xr + 4);
    float4 v2 = *(const float4*)(xr + 8);
    float4 v3 = *(const float4*)(xr + 12);

    float m = fabsf(v0.x);
    m = fmaxf(m, fabsf(v0.y)); m = fmaxf(m, fabsf(v0.z)); m = fmaxf(m, fabsf(v0.w));
    m = fmaxf(m, fabsf(v1.x)); m = fmaxf(m, fabsf(v1.y)); m = fmaxf(m, fabsf(v1.z)); m = fmaxf(m, fabsf(v1.w));
    m = fmaxf(m, fabsf(v2.x)); m = fmaxf(m, fabsf(v2.y)); m = fmaxf(m, fabsf(v2.z)); m = fmaxf(m, fabsf(v2.w));
    m = fmaxf(m, fabsf(v3.x)); m = fmaxf(m, fabsf(v3.y)); m = fmaxf(m, fabsf(v3.z)); m = fmaxf(m, fabsf(v3.w));

    #pragma unroll
    for (int d = 32; d > 0; d >>= 1) m = fmaxf(m, __shfl_xor(m, d));
    __shared__ float red[4];
    const int lane = tid & 63, wid = tid >> 6;
    if (lane == 0) red[wid] = m;
    __syncthreads();
    float rmax = fmaxf(fmaxf(red[0], red[1]), fmaxf(red[2], red[3]));
    rmax = fmaxf(rmax, 1e-20f);
    if (tid == 0) sx[row] = rmax * (1.0f / 127.0f);

    const float q = 127.0f / rmax;
    union { char c[16]; int4 v; } u;
    const float vals[16] = {v0.x, v0.y, v0.z, v0.w, v1.x, v1.y, v1.z, v1.w,
                            v2.x, v2.y, v2.z, v2.w, v3.x, v3.y, v3.z, v3.w};
    #pragma unroll
    for (int i = 0; i < 16; ++i) u.c[i] = (char)__float2int_rn(vals[i] * q);
    *(int4*)(xq + (long long)row * K_DIM + tid * 16) = u.v;
}

// ---------------------------------------------------------------------------
// Kernel 2: weight row -> sign (i8, exact) + per-row mean|w| (fp32)
// ---------------------------------------------------------------------------
__global__ __launch_bounds__(256) void convert_w_i8(const float* __restrict__ w,
                                                    char* __restrict__ wq,
                                                    float* __restrict__ sw) {
    const int row = blockIdx.x;
    const int tid = threadIdx.x;
    const float* wr = w + (long long)row * K_DIM + tid * 16;

    float sum = 0.f;
    union { char c[16]; int4 v; } u;
    #pragma unroll
    for (int j = 0; j < 4; ++j) {
        float4 v = *(const float4*)(wr + j * 4);
        sum += fabsf(v.x) + fabsf(v.y) + fabsf(v.z) + fabsf(v.w);
        u.c[j * 4 + 0] = (char)((v.x > 0.f) - (v.x < 0.f));
        u.c[j * 4 + 1] = (char)((v.y > 0.f) - (v.y < 0.f));
        u.c[j * 4 + 2] = (char)((v.z > 0.f) - (v.z < 0.f));
        u.c[j * 4 + 3] = (char)((v.w > 0.f) - (v.w < 0.f));
    }
    *(int4*)(wq + (long long)row * K_DIM + tid * 16) = u.v;

    #pragma unroll
    for (int d = 32; d > 0; d >>= 1) sum += __shfl_down(sum, d);
    __shared__ float red[4];
    const int lane = tid & 63, wid = tid >> 6;
    if (lane == 0) red[wid] = sum;
    __syncthreads();
    if (tid == 0) sw[row] = (red[0] + red[1] + red[2] + red[3]) * (1.0f / (float)K_DIM);
}

// ===========================================================================
// 256x256 i8 GEMM, 4 WAVES (2x2), wave tile 128x128, acc[8][8] (256 VGPR).
// ROUND-11 DELTA vs round-10: __launch_bounds__(256, 1) — 1 wave/SIMD,
// 512-reg budget, so acc[8][8] (256) + frags (48) + misc (~30) fits WITHOUT
// the scratch spill that destroyed round-10 (2 waves/SIMD = 256-reg cap).
// Everything else byte-identical to round-10 (geometry/swizzle/epilogue all
// refcheck-verified there: absmax 0.043 passed).
// LDS redundancy halves vs round-9 (A,B each read 2x): serial-sum model
// 2610 (MFMA) + ~1640 (LDS reads+DMA) = 4250 cyc/K-tile/CU -> ~113 us GEMM.
// ===========================================================================
struct SOp { const char* g; int row0; int kt; char* l; };

// stage one half-tile (128 rows x 64B): 2 gload_lds per wave (4 waves)
__device__ __forceinline__ void stage_half(const SOp s, int wid, int lane) {
    const int srcoff = s.kt + ((((lane & 3) ^ ((lane >> 3) & 3))) << 4);
    #pragma unroll
    for (int op = 0; op < 2; ++op) {
        const int r = s.row0 + wid * 32 + op * 16 + (lane >> 2);
        const char* src = s.g + (long long)r * K_DIM + srcoff;
        __builtin_amdgcn_global_load_lds(
            (const __attribute__((address_space(1))) void*)src,
            (__attribute__((address_space(3))) void*)(s.l + wid * 2048 + op * 1024),
            16, 0, 0);
    }
}

__device__ __forceinline__ iv4 ldsr(const char* t, int row, int c) {
    const int off = row * 64 + ((c ^ ((row >> 1) & 3)) << 4);
    return *(const iv4*)(t + off);
}

// a-half h (64 rows = 4 frags); b-half v (64 rows = 4 frags)
__device__ __forceinline__ void read_ah(iv4 (&a)[4], const char* tA,
                                        int wm, int h, int l15, int c) {
    #pragma unroll
    for (int mi = 0; mi < 4; ++mi)
        a[mi] = ldsr(tA, wm * 128 + h * 64 + mi * 16 + l15, c);
}
__device__ __forceinline__ void read_bv(iv4 (&b)[4], const char* tB,
                                        int wn, int v, int l15, int c) {
    #pragma unroll
    for (int ni = 0; ni < 4; ++ni)
        b[ni] = ldsr(tB, wn * 128 + v * 64 + ni * 16 + l15, c);
}

template<int H, int V>
__device__ __forceinline__ void mfma_q(iv4 (&acc)[8][8],
                                       const iv4 (&a)[4], const iv4 (&b)[4]) {
    #pragma unroll
    for (int mi = 0; mi < 4; ++mi)
        #pragma unroll
        for (int ni = 0; ni < 4; ++ni)
            acc[H * 4 + mi][V * 4 + ni] = __builtin_amdgcn_mfma_i32_16x16x64_i8(
                a[mi], b[ni], acc[H * 4 + mi][V * 4 + ni], 0, 0, 0);
}

// S0..S3: per-phase stage enables. WN: 2 steady / 0 drain / -1 none.
template<bool S0, bool S1, bool S2, bool S3, int WN>
__device__ __forceinline__ void ktile(const char* __restrict__ cA,
                                      const char* __restrict__ cB,
                                      char* __restrict__ oA,
                                      char* __restrict__ oB,
                                      char* __restrict__ curA,
                                      const char* gA, const char* gB,
                                      int ktn, int ktn2,
                                      iv4 (&acc)[8][8],
                                      int wm, int wn, int wid, int lane)
{
    const int l15 = lane & 15;
    const int c   = lane >> 4;
    iv4 a[4], b0[4], b1[4];

    // ---- P0: read a0 + b0 | stage Ah1(t+1) | q00
    read_ah(a, cA, wm, 0, l15, c);
    read_bv(b0, cB, wn, 0, l15, c);
    if constexpr (S0) stage_half({gA, 128, ktn, oA + 8192}, wid, lane);
    __builtin_amdgcn_s_barrier();
    __builtin_amdgcn_s_setprio(1);
    mfma_q<0, 0>(acc, a, b0);
    __builtin_amdgcn_s_setprio(0);
    __builtin_amdgcn_s_barrier();

    // ---- P1: read b1 | stage Bh0(t+1) | q01
    read_bv(b1, cB, wn, 1, l15, c);
    if constexpr (S1) stage_half({gB, 0, ktn, oB}, wid, lane);
    __builtin_amdgcn_s_barrier();
    __builtin_amdgcn_s_setprio(1);
    mfma_q<0, 1>(acc, a, b1);
    __builtin_amdgcn_s_setprio(0);
    __builtin_amdgcn_s_barrier();

    // ---- P2: read a1 (reuses a; a0 dead) | stage Bh1(t+1) | q11
    read_ah(a, cA, wm, 1, l15, c);
    if constexpr (S2) stage_half({gB, 128, ktn, oB + 8192}, wid, lane);
    __builtin_amdgcn_s_barrier();
    __builtin_amdgcn_s_setprio(1);
    mfma_q<1, 1>(acc, a, b1);
    __builtin_amdgcn_s_setprio(0);
    __builtin_amdgcn_s_barrier();

    // ---- P3: stage Ah0(t+2) into CURRENT buf (a0 rows last read @P0) | q10
    if constexpr (S3) stage_half({gA, 0, ktn2, curA}, wid, lane);
    __builtin_amdgcn_s_barrier();
    __builtin_amdgcn_s_setprio(1);
    mfma_q<1, 0>(acc, a, b0);
    __builtin_amdgcn_s_setprio(0);
    if constexpr (WN == 2)      asm volatile("s_waitcnt vmcnt(2)" ::: "memory");
    else if constexpr (WN == 0) asm volatile("s_waitcnt vmcnt(0)" ::: "memory");
    if constexpr (WN >= 0) __builtin_amdgcn_s_barrier();
}

__global__ __launch_bounds__(256, 1) void bitlinear_gemm_i8(
    const char* __restrict__ A, const char* __restrict__ B,
    const float* __restrict__ sx, const float* __restrict__ sw,
    float* __restrict__ C, int M)
{
    extern __shared__ char smem[];
    char* As0 = smem;              // [256][64B] each (16 KiB)
    char* As1 = smem + 16384;
    char* Bs0 = smem + 32768;
    char* Bs1 = smem + 49152;

    const int tid = threadIdx.x, lane = tid & 63, wid = tid >> 6;
    const int wm = wid >> 1, wn = wid & 1;     // 2x2 wave grid

    // T1: bijective XCD swizzle (grid % 8 == 0 guaranteed by launcher)
    const int nbid = (int)blockIdx.x;
    const int cpx  = (int)gridDim.x >> 3;
    const int swz  = (nbid & 7) * cpx + (nbid >> 3);
    const int ntn  = N_DIM / 256;       // 16
    const int tm = swz / ntn, tn = swz % ntn;

    const char* gA = A + (long long)tm * 256 * K_DIM;
    const char* gB = B + (long long)tn * 256 * K_DIM;

    iv4 acc[8][8];
    #pragma unroll
    for (int i = 0; i < 8; ++i)
        #pragma unroll
        for (int j = 0; j < 8; ++j) acc[i][j] = (iv4){0, 0, 0, 0};

    // prologue: t0 all 4 halves + Ah0(t1) = 5 stage calls = 10 loads;
    // vmcnt(2) drains t0's 8, leaves Ah0(t1)'s 2 in flight.
    stage_half({gA,   0,  0, As0},        wid, lane);
    stage_half({gA, 128,  0, As0 + 8192}, wid, lane);
    stage_half({gB,   0,  0, Bs0},        wid, lane);
    stage_half({gB, 128,  0, Bs0 + 8192}, wid, lane);
    stage_half({gA,   0, BK, As1},        wid, lane);
    asm volatile("s_waitcnt vmcnt(2)" ::: "memory");
    __builtin_amdgcn_s_barrier();

    // t=0 (buf0)
    ktile<true, true, true, true, 2>(As0, Bs0, As1, Bs1, As0,
                                     gA, gB, 1 * BK, 2 * BK,
                                     acc, wm, wn, wid, lane);
    // t=1..60 in pairs (buf1, buf0)
    #pragma unroll 1
    for (int i = 0; i < 30; ++i) {
        const int t = 2 * i + 1;
        ktile<true, true, true, true, 2>(As1, Bs1, As0, Bs0, As1,
                                         gA, gB, (t + 1) * BK, (t + 2) * BK,
                                         acc, wm, wn, wid, lane);
        ktile<true, true, true, true, 2>(As0, Bs0, As1, Bs1, As0,
                                         gA, gB, (t + 2) * BK, (t + 3) * BK,
                                         acc, wm, wn, wid, lane);
    }
    // t=61 (buf1): steady (stages t62 halves + Ah0(t63))
    ktile<true, true, true, true, 2>(As1, Bs1, As0, Bs0, As1,
                                     gA, gB, 62 * BK, 63 * BK,
                                     acc, wm, wn, wid, lane);
    // t=62 (buf0): stage t63's Ah1,Bh0,Bh1 only; vmcnt(0) drains all
    ktile<true, true, true, false, 0>(As0, Bs0, As1, Bs1, As0,
                                      gA, gB, 63 * BK, 0,
                                      acc, wm, wn, wid, lane);
    // t=63 (buf1): plain compute, no trailing sync
    ktile<false, false, false, false, -1>(As1, Bs1, As0, Bs0, As1,
                                          gA, gB, 0, 0,
                                          acc, wm, wn, wid, lane);

    // epilogue: out = i32 * sw[col] * sx[row]. C/D: col=lane&15, row=(lane>>4)*4+j
    const long long m0 = (long long)tm * 256 + wm * 128;
    const long long n0 = (long long)tn * 256 + wn * 128;
    float swv[8];
    #pragma unroll
    for (int ni = 0; ni < 8; ++ni) swv[ni] = sw[n0 + ni * 16 + (lane & 15)];
    #pragma unroll
    for (int mi = 0; mi < 8; ++mi) {
        const long long rowb = m0 + mi * 16 + (lane >> 4) * 4;
        float sxr[4];
        #pragma unroll
        for (int j = 0; j < 4; ++j) sxr[j] = sx[rowb + j];
        #pragma unroll
        for (int ni = 0; ni < 8; ++ni) {
            const long long col = n0 + ni * 16 + (lane & 15);
            #pragma unroll
            for (int j = 0; j < 4; ++j)
                C[(rowb + j) * N_DIM + col] = (float)acc[mi][ni][j] * swv[ni] * sxr[j];
        }
    }
}

// ---------------------------------------------------------------------------
// Naive fp32 fallback (shape/workspace escape hatch)
// ---------------------------------------------------------------------------
__global__ void bitlinear_naive_kernel(const float* __restrict__ x,
                                       const float* __restrict__ w,
                                       float* __restrict__ out, long long total) {
    const long long idx = (long long)blockIdx.x * blockDim.x + threadIdx.x;
    if (idx >= total) return;
    const long long m = idx / N_DIM;
    const long long o = idx % N_DIM;
    const float* xr = x + m * K_DIM;
    const float* wrow = w + o * K_DIM;
    float sum = 0.f, sa = 0.f;
    for (int k = 0; k < K_DIM; ++k) {
        float wv = wrow[k];
        sa += fabsf(wv);
        sum += xr[k] * ((wv > 0.f) ? 1.f : ((wv < 0.f) ? -1.f : 0.f));
    }
    out[idx] = sum * (sa * (1.0f / (float)K_DIM));
}

// ---------------------------------------------------------------------------
extern "C" void kernel_launch(void* const* d_in, const int* in_sizes, int n_in,
                              void* d_out, int out_size, void* d_ws, size_t ws_size,
                              hipStream_t stream) {
    const float* x = (const float*)d_in[0];   // [B,S,K] fp32
    const float* w = (const float*)d_in[1];   // [N,K] fp32
    float* out = (float*)d_out;               // [B,S,N] fp32

    const int M = in_sizes[0] / K_DIM;        // 8192

    const size_t xq_bytes = (size_t)M * K_DIM;
    const size_t wq_bytes = (size_t)N_DIM * K_DIM;
    const size_t sx_bytes = (size_t)M * sizeof(float);
    const size_t sw_bytes = (size_t)N_DIM * sizeof(float);

    if (ws_size < xq_bytes + wq_bytes + sx_bytes + sw_bytes || (M % 256) != 0) {
        const long long total = (long long)M * N_DIM;
        bitlinear_naive_kernel<<<(int)((total + 255) / 256), 256, 0, stream>>>(x, w, out, total);
        return;
    }

    char*  xq = (char*)d_ws;
    char*  wq = (char*)d_ws + xq_bytes;
    float* sx = (float*)((char*)d_ws + xq_bytes + wq_bytes);
    float* sw = (float*)((char*)d_ws + xq_bytes + wq_bytes + sx_bytes);

    convert_x_i8<<<M, 256, 0, stream>>>(x, xq, sx);
    convert_w_i8<<<N_DIM, 256, 0, stream>>>(w, wq, sw);

    hipFuncSetAttribute((const void*)bitlinear_gemm_i8,
                        hipFuncAttributeMaxDynamicSharedMemorySize, 65536);
    const int grid = (M / 256) * (N_DIM / 256);   // 32*16 = 512, %8==0
    bitlinear_gemm_i8<<<grid, 256, 65536, stream>>>(xq, wq, sx, sw, out, M);
}